// Round 1
// baseline (3454.991 us; speedup 1.0000x reference)
//
#include <hip/hip_runtime.h>
#include <hip/hip_bf16.h>

#define NB 16
#define N2V 618
#define N3V 2466
#define FEAT 963
#define HID 192
#define EMBV 8
#define IN_DIM 1163
#define MTOT (NB * N3V)   // 39456

// ---------------------------------------------------------------------------
// q,k,v projections: mv has only grade-1 part (x2) nonzero -> rows 1..3 of W
// ---------------------------------------------------------------------------
__global__ void qkv_kernel(const float* __restrict__ x2,
                           const float* __restrict__ Wq, const float* __restrict__ bq,
                           const float* __restrict__ Wk, const float* __restrict__ bk,
                           const float* __restrict__ Wv, const float* __restrict__ bv,
                           float* __restrict__ q, float* __restrict__ k, float* __restrict__ v)
{
    int idx = blockIdx.x * 256 + threadIdx.x;
    if (idx >= NB * N2V) return;
    float c0 = x2[idx * 3 + 0], c1 = x2[idx * 3 + 1], c2 = x2[idx * 3 + 2];
#pragma unroll
    for (int d = 0; d < 8; ++d) {
        q[idx * 8 + d] = bq[d] + c0 * Wq[1 * 8 + d] + c1 * Wq[2 * 8 + d] + c2 * Wq[3 * 8 + d];
        k[idx * 8 + d] = bk[d] + c0 * Wk[1 * 8 + d] + c1 * Wk[2 * 8 + d] + c2 * Wk[3 * 8 + d];
        v[idx * 8 + d] = bv[d] + c0 * Wv[1 * 8 + d] + c1 * Wv[2 * 8 + d] + c2 * Wv[3 * 8 + d];
    }
}

// ---------------------------------------------------------------------------
// fused softmax attention: one block per (b, n) row; two passes, scores in regs
// ---------------------------------------------------------------------------
__global__ __launch_bounds__(256) void attn_kernel(const float* __restrict__ q,
                                                   const float* __restrict__ k,
                                                   const float* __restrict__ v,
                                                   float* __restrict__ att)
{
    int bn = blockIdx.x;              // 0 .. NB*N2V-1
    int b = bn / N2V;
    int tid = threadIdx.x;
    int lane = tid & 63, wid = tid >> 6;
    __shared__ float red[4][12];
    __shared__ float fin[12];

    float qv[8];
#pragma unroll
    for (int d = 0; d < 8; ++d) qv[d] = q[(size_t)bn * 8 + d];
    const float* kb = k + (size_t)b * N2V * 8;
    const float* vb = v + (size_t)b * N2V * 8;

    const float scale = 0.35355339059327373f; // 1/sqrt(8)
    float svals[3];
    float mx = -3.0e38f;
    int cnt = 0;
    for (int m = tid; m < N2V; m += 256) {
        const float4 k0 = *(const float4*)(kb + m * 8);
        const float4 k1 = *(const float4*)(kb + m * 8 + 4);
        float s = qv[0] * k0.x + qv[1] * k0.y + qv[2] * k0.z + qv[3] * k0.w
                + qv[4] * k1.x + qv[5] * k1.y + qv[6] * k1.z + qv[7] * k1.w;
        s *= scale;
        svals[cnt++] = s;
        mx = fmaxf(mx, s);
    }
#pragma unroll
    for (int o = 32; o; o >>= 1) mx = fmaxf(mx, __shfl_down(mx, o));
    if (lane == 0) red[wid][0] = mx;
    __syncthreads();
    if (tid == 0)
        fin[0] = fmaxf(fmaxf(red[0][0], red[1][0]), fmaxf(red[2][0], red[3][0]));
    __syncthreads();
    mx = fin[0];

    float sum = 0.f, acc[8];
#pragma unroll
    for (int d = 0; d < 8; ++d) acc[d] = 0.f;
    int i = 0;
    for (int m = tid; m < N2V; m += 256, ++i) {
        float p = __expf(svals[i] - mx);
        sum += p;
        const float4 v0 = *(const float4*)(vb + m * 8);
        const float4 v1 = *(const float4*)(vb + m * 8 + 4);
        acc[0] += p * v0.x; acc[1] += p * v0.y; acc[2] += p * v0.z; acc[3] += p * v0.w;
        acc[4] += p * v1.x; acc[5] += p * v1.y; acc[6] += p * v1.z; acc[7] += p * v1.w;
    }
#pragma unroll
    for (int o = 32; o; o >>= 1) {
        sum += __shfl_down(sum, o);
#pragma unroll
        for (int d = 0; d < 8; ++d) acc[d] += __shfl_down(acc[d], o);
    }
    if (lane == 0) {
        red[wid][0] = sum;
#pragma unroll
        for (int d = 0; d < 8; ++d) red[wid][1 + d] = acc[d];
    }
    __syncthreads();
    if (tid < 9)
        fin[tid] = red[0][tid] + red[1][tid] + red[2][tid] + red[3][tid];
    __syncthreads();
    if (tid < 8)
        att[(size_t)bn * 8 + tid] = fin[1 + tid] / fin[0];
}

// ---------------------------------------------------------------------------
// extract sparse adjacency: per row, <=6 nonzeros (value 1/6). Sorted => deterministic.
// ---------------------------------------------------------------------------
__global__ void adj_extract(const float* __restrict__ adj, int* __restrict__ cols,
                            float* __restrict__ vals)
{
    int m = blockIdx.x;
    __shared__ int cnt;
    __shared__ int lc[8];
    __shared__ float lv[8];
    if (threadIdx.x == 0) cnt = 0;
    __syncthreads();
    for (int c = threadIdx.x; c < N3V; c += 256) {
        float a = adj[(size_t)m * N3V + c];
        if (a != 0.f) {
            int p = atomicAdd(&cnt, 1);
            if (p < 6) { lc[p] = c; lv[p] = a; }
        }
    }
    __syncthreads();
    if (threadIdx.x == 0) {
        int n = cnt < 6 ? cnt : 6;
        for (int i = 1; i < n; ++i) {           // insertion sort by col
            int ci = lc[i]; float vi = lv[i]; int j = i - 1;
            while (j >= 0 && lc[j] > ci) { lc[j + 1] = lc[j]; lv[j + 1] = lv[j]; --j; }
            lc[j + 1] = ci; lv[j + 1] = vi;
        }
        for (int i = 0; i < 6; ++i) {
            cols[m * 6 + i] = (i < n) ? lc[i] : 0;
            vals[m * 6 + i] = (i < n) ? lv[i] : 0.f;
        }
    }
}

// ---------------------------------------------------------------------------
// virtual feat element: concat(x[963], x_hidden[192], x2_att[8]); bn = b*618+n
// ---------------------------------------------------------------------------
__device__ __forceinline__ float feat_elem(int bn, int kk, const float* __restrict__ x,
                                           const float* __restrict__ xh,
                                           const float* __restrict__ att)
{
    if (kk < FEAT) return x[(size_t)bn * FEAT + kk];
    if (kk < FEAT + HID) return xh[(size_t)bn * HID + (kk - FEAT)];
    return att[(size_t)bn * 8 + (kk - FEAT - HID)];
}

// ---------------------------------------------------------------------------
// tiled fp32 GEMM: C[M,384] = A[M,K] * [Wa | Wb]  (each [K,192])
// BM=128, BN=128, KB=32, 256 threads, 8x8 per thread.
// ENTRY: A rows gathered on the fly (concat feat + unpool midpoints), K=1163.
// ---------------------------------------------------------------------------
template <bool ENTRY>
__global__ __launch_bounds__(256) void gemm_kernel(
    const float* __restrict__ A, const float* __restrict__ Wa, const float* __restrict__ Wb,
    float* __restrict__ C,
    const float* __restrict__ x, const float* __restrict__ xh, const float* __restrict__ att,
    const int* __restrict__ unpool, int K)
{
    __shared__ __align__(16) float As[128][33];
    __shared__ __align__(16) float Ws[32][128];
    __shared__ int rA[128], rB[128];

    int tid = threadIdx.x;
    int row0 = blockIdx.x * 128;
    int nbase = blockIdx.y * 128;   // 0,128,256 of 384
    int tr = tid >> 4, tc = tid & 15;

    if (ENTRY) {
        if (tid < 128) {
            int gr = row0 + tid;
            int a = -1, bidx = -1;
            if (gr < MTOT) {
                int b = gr / N3V, n = gr % N3V;
                if (n < N2V) a = b * N2V + n;
                else {
                    int j = n - N2V;
                    a = b * N2V + unpool[2 * j];
                    bidx = b * N2V + unpool[2 * j + 1];
                }
            }
            rA[tid] = a; rB[tid] = bidx;
        }
        __syncthreads();
    }

    float acc[8][8];
#pragma unroll
    for (int i = 0; i < 8; ++i)
#pragma unroll
        for (int j = 0; j < 8; ++j) acc[i][j] = 0.f;

    for (int kk = 0; kk < K; kk += 32) {
        // stage A tile (128 x 32)
#pragma unroll
        for (int it = 0; it < 16; ++it) {
            int e = tid + it * 256;
            int r = e >> 5, kloc = e & 31;
            int kg = kk + kloc;
            float val = 0.f;
            if (ENTRY) {
                int a = rA[r];
                if (a >= 0 && kg < K) {
                    val = feat_elem(a, kg, x, xh, att);
                    int bb = rB[r];
                    if (bb >= 0) val = 0.5f * (val + feat_elem(bb, kg, x, xh, att));
                }
            } else {
                int gr = row0 + r;
                if (gr < MTOT && kg < K) val = A[(size_t)gr * 192 + kg];
            }
            As[r][kloc] = val;
        }
        // stage W tile (32 x 128): n = nbase + c; cols <192 from Wa else Wb
#pragma unroll
        for (int it = 0; it < 16; ++it) {
            int e = tid + it * 256;
            int c = e & 127, kloc = e >> 7;
            int kg = kk + kloc;
            float w = 0.f;
            if (kg < K) {
                int n = nbase + c;
                w = (n < 192) ? Wa[(size_t)kg * 192 + n] : Wb[(size_t)kg * 192 + (n - 192)];
            }
            Ws[kloc][c] = w;
        }
        __syncthreads();

#pragma unroll 4
        for (int k2 = 0; k2 < 32; ++k2) {
            float4 w0 = *(const float4*)&Ws[k2][tc * 8];
            float4 w1 = *(const float4*)&Ws[k2][tc * 8 + 4];
            float a[8];
#pragma unroll
            for (int i = 0; i < 8; ++i) a[i] = As[tr * 8 + i][k2];
#pragma unroll
            for (int i = 0; i < 8; ++i) {
                acc[i][0] += a[i] * w0.x; acc[i][1] += a[i] * w0.y;
                acc[i][2] += a[i] * w0.z; acc[i][3] += a[i] * w0.w;
                acc[i][4] += a[i] * w1.x; acc[i][5] += a[i] * w1.y;
                acc[i][6] += a[i] * w1.z; acc[i][7] += a[i] * w1.w;
            }
        }
        __syncthreads();
    }

#pragma unroll
    for (int i = 0; i < 8; ++i) {
        int gr = row0 + tr * 8 + i;
        if (gr < MTOT) {
            float* cp = C + (size_t)gr * 384 + nbase + tc * 8;
            float4 o0 = { acc[i][0], acc[i][1], acc[i][2], acc[i][3] };
            float4 o1 = { acc[i][4], acc[i][5], acc[i][6], acc[i][7] };
            *(float4*)cp = o0;
            *(float4*)(cp + 4) = o1;
        }
    }
}

// ---------------------------------------------------------------------------
// combine: out = relu(spmv(adj, u[:,:192]) + u[:,192:384] + bias)
// mode 1: out = 0.5*(hprev + relu(...))      (residual merge)
// ---------------------------------------------------------------------------
__global__ void combine_kernel(const float* __restrict__ u, const int* __restrict__ cols,
                               const float* __restrict__ vals, const float* __restrict__ bias,
                               const float* __restrict__ hprev, float* __restrict__ out, int mode)
{
    int bm = blockIdx.x;             // b*N3V + m
    int f = threadIdx.x;             // 0..191
    int b = bm / N3V, m = bm % N3V;
    float s = 0.f;
#pragma unroll
    for (int j = 0; j < 6; ++j) {
        int c = cols[m * 6 + j];
        float w = vals[m * 6 + j];
        s += w * u[((size_t)b * N3V + c) * 384 + f];
    }
    s += u[(size_t)bm * 384 + 192 + f] + bias[f];
    s = fmaxf(s, 0.f);
    if (mode) s = 0.5f * (hprev[(size_t)bm * 192 + f] + s);
    out[(size_t)bm * 192 + f] = s;
}

// ---------------------------------------------------------------------------
// final head: t[bm, 0:3] = x4row @ Wg ; t[bm, 3:6] = x4row @ loopWg
// ---------------------------------------------------------------------------
__global__ void head_a(const float* __restrict__ x4, const float* __restrict__ Wg,
                       const float* __restrict__ loopWg, float* __restrict__ t)
{
    int idx = blockIdx.x * 256 + threadIdx.x;
    if (idx >= MTOT * 6) return;
    int bm = idx / 6, c = idx % 6;
    const float* W = (c < 3) ? Wg : loopWg;
    int cc = (c < 3) ? c : c - 3;
    float s = 0.f;
    for (int k = 0; k < 192; ++k) s += x4[(size_t)bm * 192 + k] * W[k * 3 + cc];
    t[idx] = s;
}

__global__ void head_b(const float* __restrict__ t, const int* __restrict__ cols,
                       const float* __restrict__ vals, const float* __restrict__ bg,
                       float* __restrict__ out)
{
    int idx = blockIdx.x * 256 + threadIdx.x;
    if (idx >= MTOT * 3) return;
    int bm = idx / 3, c = idx % 3;
    int b = bm / N3V, m = bm % N3V;
    float s = 0.f;
#pragma unroll
    for (int j = 0; j < 6; ++j)
        s += vals[m * 6 + j] * t[((size_t)b * N3V + cols[m * 6 + j]) * 6 + c];
    s += t[(size_t)bm * 6 + 3 + c] + bg[c];
    out[idx] = s;
}

// ---------------------------------------------------------------------------
extern "C" void kernel_launch(void* const* d_in, const int* in_sizes, int n_in,
                              void* d_out, int out_size, void* d_ws, size_t ws_size,
                              hipStream_t stream)
{
    const float* x        = (const float*)d_in[0];
    const float* x2       = (const float*)d_in[1];
    const float* xh       = (const float*)d_in[2];
    const float* Wq       = (const float*)d_in[3];
    const float* bq       = (const float*)d_in[4];
    const float* Wk       = (const float*)d_in[5];
    const float* bk       = (const float*)d_in[6];
    const float* Wv       = (const float*)d_in[7];
    const float* bv       = (const float*)d_in[8];
    const float* adj      = (const float*)d_in[9];
    const int*   unpool   = (const int*)d_in[10];
    const float* W_in     = (const float*)d_in[11];
    const float* loopW_in = (const float*)d_in[12];
    const float* b_in     = (const float*)d_in[13];
    const float* res_W    = (const float*)d_in[14];
    const float* res_loopW= (const float*)d_in[15];
    const float* res_b    = (const float*)d_in[16];
    const float* W_out    = (const float*)d_in[17];
    const float* loopW_out= (const float*)d_in[18];
    const float* b_out    = (const float*)d_in[19];
    const float* Wg       = (const float*)d_in[20];
    const float* loopWg   = (const float*)d_in[21];
    const float* bg       = (const float*)d_in[22];
    float* out = (float*)d_out;

    float* ws = (float*)d_ws;
    size_t o = 0;
    auto alloc = [&](size_t n) { float* p = ws + o; o += (n + 63) & ~(size_t)63; return p; };
    float* q    = alloc((size_t)NB * N2V * 8);
    float* kbuf = alloc((size_t)NB * N2V * 8);
    float* vbuf = alloc((size_t)NB * N2V * 8);
    float* att  = alloc((size_t)NB * N2V * 8);
    int*   cols = (int*)alloc((size_t)N3V * 6);
    float* vals = alloc((size_t)N3V * 6);
    float* u    = alloc((size_t)MTOT * 384);
    float* h    = alloc((size_t)MTOT * 192);
    float* y    = alloc((size_t)MTOT * 192);
    float* ts   = alloc((size_t)MTOT * 6);
    if (ws_size < o * sizeof(float)) return;   // workspace too small -> clean failure

    qkv_kernel<<<(NB * N2V + 255) / 256, 256, 0, stream>>>(x2, Wq, bq, Wk, bk, Wv, bv, q, kbuf, vbuf);
    attn_kernel<<<NB * N2V, 256, 0, stream>>>(q, kbuf, vbuf, att);
    adj_extract<<<N3V, 256, 0, stream>>>(adj, cols, vals);

    dim3 gg((MTOT + 127) / 128, 3);
    gemm_kernel<true><<<gg, 256, 0, stream>>>(nullptr, W_in, loopW_in, u, x, xh, att, unpool, IN_DIM);
    combine_kernel<<<MTOT, 192, 0, stream>>>(u, cols, vals, b_in, nullptr, h, 0);

    for (int i = 0; i < 6; ++i) {
        const float* W0 = res_W     + (size_t)(i * 2 + 0) * 192 * 192;
        const float* L0 = res_loopW + (size_t)(i * 2 + 0) * 192 * 192;
        const float* B0 = res_b     + (size_t)(i * 2 + 0) * 192;
        const float* W1 = res_W     + (size_t)(i * 2 + 1) * 192 * 192;
        const float* L1 = res_loopW + (size_t)(i * 2 + 1) * 192 * 192;
        const float* B1 = res_b     + (size_t)(i * 2 + 1) * 192;
        gemm_kernel<false><<<gg, 256, 0, stream>>>(h, W0, L0, u, nullptr, nullptr, nullptr, nullptr, 192);
        combine_kernel<<<MTOT, 192, 0, stream>>>(u, cols, vals, B0, nullptr, y, 0);
        gemm_kernel<false><<<gg, 256, 0, stream>>>(y, W1, L1, u, nullptr, nullptr, nullptr, nullptr, 192);
        combine_kernel<<<MTOT, 192, 0, stream>>>(u, cols, vals, B1, h, h, 1);
    }

    gemm_kernel<false><<<gg, 256, 0, stream>>>(h, W_out, loopW_out, u, nullptr, nullptr, nullptr, nullptr, 192);
    combine_kernel<<<MTOT, 192, 0, stream>>>(u, cols, vals, b_out, nullptr, y, 0);

    head_a<<<(MTOT * 6 + 255) / 256, 256, 0, stream>>>(y, Wg, loopWg, ts);
    head_b<<<(MTOT * 3 + 255) / 256, 256, 0, stream>>>(ts, cols, vals, bg, out);
}

// Round 2
// 986.090 us; speedup vs baseline: 3.5037x; 3.5037x over previous
//
#include <hip/hip_runtime.h>
#include <hip/hip_bf16.h>

#define NB 16
#define N2V 618
#define N3V 2466
#define FEAT 963
#define HID 192
#define IN_DIM 1163
#define KPAD 1184          // 1163 padded to multiple of 32
#define MTOT (NB * N3V)    // 39456

typedef __attribute__((ext_vector_type(8))) short bf16x8;
typedef __attribute__((ext_vector_type(4))) float f32x4;

__device__ __forceinline__ float bf2f(ushort u) {
    return __uint_as_float(((unsigned)u) << 16);
}
__device__ __forceinline__ ushort f2bf(float f) {   // round-to-nearest-even
    unsigned u = __float_as_uint(f);
    return (ushort)((u + 0x7FFFu + ((u >> 16) & 1u)) >> 16);
}

// ---------------------------------------------------------------------------
// q,k,v projections: mv grade-1 only -> rows 1..3 of W
// ---------------------------------------------------------------------------
__global__ void qkv_kernel(const float* __restrict__ x2,
                           const float* __restrict__ Wq, const float* __restrict__ bq,
                           const float* __restrict__ Wk, const float* __restrict__ bk,
                           const float* __restrict__ Wv, const float* __restrict__ bv,
                           float* __restrict__ q, float* __restrict__ k, float* __restrict__ v)
{
    int idx = blockIdx.x * 256 + threadIdx.x;
    if (idx >= NB * N2V) return;
    float c0 = x2[idx * 3 + 0], c1 = x2[idx * 3 + 1], c2 = x2[idx * 3 + 2];
#pragma unroll
    for (int d = 0; d < 8; ++d) {
        q[idx * 8 + d] = bq[d] + c0 * Wq[8 + d] + c1 * Wq[16 + d] + c2 * Wq[24 + d];
        k[idx * 8 + d] = bk[d] + c0 * Wk[8 + d] + c1 * Wk[16 + d] + c2 * Wk[24 + d];
        v[idx * 8 + d] = bv[d] + c0 * Wv[8 + d] + c1 * Wv[16 + d] + c2 * Wv[24 + d];
    }
}

// ---------------------------------------------------------------------------
// fused softmax attention: one block per (b,n) row
// ---------------------------------------------------------------------------
__global__ __launch_bounds__(256) void attn_kernel(const float* __restrict__ q,
                                                   const float* __restrict__ k,
                                                   const float* __restrict__ v,
                                                   float* __restrict__ att)
{
    int bn = blockIdx.x;
    int b = bn / N2V;
    int tid = threadIdx.x;
    int lane = tid & 63, wid = tid >> 6;
    __shared__ float red[4][12];
    __shared__ float fin[12];

    float qv[8];
#pragma unroll
    for (int d = 0; d < 8; ++d) qv[d] = q[(size_t)bn * 8 + d];
    const float* kb = k + (size_t)b * N2V * 8;
    const float* vb = v + (size_t)b * N2V * 8;

    const float scale = 0.35355339059327373f;
    float svals[3];
    float mx = -3.0e38f;
    int cnt = 0;
    for (int m = tid; m < N2V; m += 256) {
        const float4 k0 = *(const float4*)(kb + m * 8);
        const float4 k1 = *(const float4*)(kb + m * 8 + 4);
        float s = qv[0] * k0.x + qv[1] * k0.y + qv[2] * k0.z + qv[3] * k0.w
                + qv[4] * k1.x + qv[5] * k1.y + qv[6] * k1.z + qv[7] * k1.w;
        s *= scale;
        svals[cnt++] = s;
        mx = fmaxf(mx, s);
    }
#pragma unroll
    for (int o = 32; o; o >>= 1) mx = fmaxf(mx, __shfl_down(mx, o));
    if (lane == 0) red[wid][0] = mx;
    __syncthreads();
    if (tid == 0)
        fin[0] = fmaxf(fmaxf(red[0][0], red[1][0]), fmaxf(red[2][0], red[3][0]));
    __syncthreads();
    mx = fin[0];

    float sum = 0.f, acc[8];
#pragma unroll
    for (int d = 0; d < 8; ++d) acc[d] = 0.f;
    int i = 0;
    for (int m = tid; m < N2V; m += 256, ++i) {
        float p = __expf(svals[i] - mx);
        sum += p;
        const float4 v0 = *(const float4*)(vb + m * 8);
        const float4 v1 = *(const float4*)(vb + m * 8 + 4);
        acc[0] += p * v0.x; acc[1] += p * v0.y; acc[2] += p * v0.z; acc[3] += p * v0.w;
        acc[4] += p * v1.x; acc[5] += p * v1.y; acc[6] += p * v1.z; acc[7] += p * v1.w;
    }
#pragma unroll
    for (int o = 32; o; o >>= 1) {
        sum += __shfl_down(sum, o);
#pragma unroll
        for (int d = 0; d < 8; ++d) acc[d] += __shfl_down(acc[d], o);
    }
    if (lane == 0) {
        red[wid][0] = sum;
#pragma unroll
        for (int d = 0; d < 8; ++d) red[wid][1 + d] = acc[d];
    }
    __syncthreads();
    if (tid < 9)
        fin[tid] = red[0][tid] + red[1][tid] + red[2][tid] + red[3][tid];
    __syncthreads();
    if (tid < 8)
        att[(size_t)bn * 8 + tid] = fin[1 + tid] / fin[0];
}

// ---------------------------------------------------------------------------
// sparse adjacency extraction (<=6 nnz/row, sorted)
// ---------------------------------------------------------------------------
__global__ void adj_extract(const float* __restrict__ adj, int* __restrict__ cols,
                            float* __restrict__ vals)
{
    int m = blockIdx.x;
    __shared__ int cnt;
    __shared__ int lc[8];
    __shared__ float lv[8];
    if (threadIdx.x == 0) cnt = 0;
    __syncthreads();
    for (int c = threadIdx.x; c < N3V; c += 256) {
        float a = adj[(size_t)m * N3V + c];
        if (a != 0.f) {
            int p = atomicAdd(&cnt, 1);
            if (p < 6) { lc[p] = c; lv[p] = a; }
        }
    }
    __syncthreads();
    if (threadIdx.x == 0) {
        int n = cnt < 6 ? cnt : 6;
        for (int i = 1; i < n; ++i) {
            int ci = lc[i]; float vi = lv[i]; int j = i - 1;
            while (j >= 0 && lc[j] > ci) { lc[j + 1] = lc[j]; lv[j + 1] = lv[j]; --j; }
            lc[j + 1] = ci; lv[j + 1] = vi;
        }
        for (int i = 0; i < 6; ++i) {
            cols[m * 6 + i] = (i < n) ? lc[i] : 0;
            vals[m * 6 + i] = (i < n) ? lv[i] : 0.f;
        }
    }
}

// ---------------------------------------------------------------------------
// F[bn][k] bf16: concat(x[963], xh[192], att[8], zeros) padded to KPAD
// ---------------------------------------------------------------------------
__global__ void build_F(const float* __restrict__ x, const float* __restrict__ xh,
                        const float* __restrict__ att, ushort* __restrict__ F)
{
    int bn = blockIdx.x;
    for (int k = threadIdx.x; k < KPAD; k += 256) {
        float v = 0.f;
        if (k < FEAT) v = x[(size_t)bn * FEAT + k];
        else if (k < FEAT + HID) v = xh[(size_t)bn * HID + (k - FEAT)];
        else if (k < IN_DIM) v = att[(size_t)bn * 8 + (k - FEAT - HID)];
        F[(size_t)bn * KPAD + k] = f2bf(v);
    }
}

// ---------------------------------------------------------------------------
// weight transposes to bf16 Wt[n][K] (n<192 from W, else loopW)
// ---------------------------------------------------------------------------
__global__ void prep_wt_entry(const float* __restrict__ W, const float* __restrict__ L,
                              ushort* __restrict__ Wt)
{
    int idx = blockIdx.x * 256 + threadIdx.x;
    if (idx >= 384 * KPAD) return;
    int n = idx / KPAD, k = idx % KPAD;
    float v = 0.f;
    if (k < IN_DIM) v = (n < 192) ? W[k * 192 + n] : L[k * 192 + (n - 192)];
    Wt[idx] = f2bf(v);
}

__global__ void prep_wt192(const float* __restrict__ W, const float* __restrict__ L,
                           ushort* __restrict__ Wt)
{
    int idx = blockIdx.x * 256 + threadIdx.x;
    if (idx >= 384 * 192) return;
    int n = idx / 192, k = idx % 192;
    float v = (n < 192) ? W[k * 192 + n] : L[k * 192 + (n - 192)];
    Wt[idx] = f2bf(v);
}

// ---------------------------------------------------------------------------
// MFMA GEMM, no LDS: C[M,384] = A[M,K] @ Wt^T, bf16 in/out, fp32 accum.
// Block = 256 thr (4 waves), tile 64 rows x 384 cols; wave w -> cols [96w,96w+96).
// ENTRY: A row = F row (n<618) or average of two parent F rows (unpool).
// ---------------------------------------------------------------------------
template <bool ENTRY>
__global__ __launch_bounds__(256) void mfma_gemm(
    const ushort* __restrict__ A, const ushort* __restrict__ F,
    const int* __restrict__ unpool, const ushort* __restrict__ Wt,
    ushort* __restrict__ C, int K)
{
    int tid = threadIdx.x;
    int wave = tid >> 6, lane = tid & 63;
    int row0 = blockIdx.x * 64;
    int ncol0 = wave * 96;
    int lr = lane & 15;             // fragment row (A) / col (B,D)
    int lk = (lane >> 4) * 8;       // fragment k offset

    int rA[4], rB[4];
#pragma unroll
    for (int mt = 0; mt < 4; ++mt) {
        int r = row0 + mt * 16 + lr;
        if (r >= MTOT) r = MTOT - 1;
        if (ENTRY) {
            int b = r / N3V, n = r % N3V;
            if (n < N2V) { rA[mt] = b * N2V + n; rB[mt] = -1; }
            else {
                int j = n - N2V;
                rA[mt] = b * N2V + unpool[2 * j];
                rB[mt] = b * N2V + unpool[2 * j + 1];
            }
        } else rA[mt] = r;
    }

    f32x4 acc[4][6];
#pragma unroll
    for (int mt = 0; mt < 4; ++mt)
#pragma unroll
        for (int nt = 0; nt < 6; ++nt)
            acc[mt][nt] = (f32x4){0.f, 0.f, 0.f, 0.f};

    for (int k0 = 0; k0 < K; k0 += 32) {
        bf16x8 a[4], b[6];
#pragma unroll
        for (int mt = 0; mt < 4; ++mt) {
            if (ENTRY) {
                bf16x8 v0 = *(const bf16x8*)(F + (size_t)rA[mt] * KPAD + k0 + lk);
                if (rB[mt] >= 0) {
                    bf16x8 v1 = *(const bf16x8*)(F + (size_t)rB[mt] * KPAD + k0 + lk);
#pragma unroll
                    for (int j = 0; j < 8; ++j) {
                        float f0 = bf2f((ushort)v0[j]);
                        float f1 = bf2f((ushort)v1[j]);
                        v0[j] = (short)f2bf(0.5f * (f0 + f1));
                    }
                }
                a[mt] = v0;
            } else {
                a[mt] = *(const bf16x8*)(A + (size_t)rA[mt] * K + k0 + lk);
            }
        }
#pragma unroll
        for (int nt = 0; nt < 6; ++nt)
            b[nt] = *(const bf16x8*)(Wt + (size_t)(ncol0 + nt * 16 + lr) * K + k0 + lk);
#pragma unroll
        for (int mt = 0; mt < 4; ++mt)
#pragma unroll
            for (int nt = 0; nt < 6; ++nt)
                acc[mt][nt] = __builtin_amdgcn_mfma_f32_16x16x32_bf16(a[mt], b[nt], acc[mt][nt], 0, 0, 0);
    }

    int crow = (lane >> 4) * 4;     // D: row = (lane>>4)*4 + reg, col = lane&15
#pragma unroll
    for (int mt = 0; mt < 4; ++mt) {
#pragma unroll
        for (int r = 0; r < 4; ++r) {
            int row = row0 + mt * 16 + crow + r;
            if (row < MTOT) {
#pragma unroll
                for (int nt = 0; nt < 6; ++nt)
                    C[(size_t)row * 384 + ncol0 + nt * 16 + lr] = f2bf(acc[mt][nt][r]);
            }
        }
    }
}

// ---------------------------------------------------------------------------
// combine: out = relu(spmv(adj, u[:, :192]) + u[:, 192:] + bias); mode1: residual
// ---------------------------------------------------------------------------
__global__ void combine_bf(const ushort* __restrict__ u, const int* __restrict__ cols,
                           const float* __restrict__ vals, const float* __restrict__ bias,
                           const ushort* __restrict__ hprev, ushort* __restrict__ out, int mode)
{
    int bm = blockIdx.x;
    int f = threadIdx.x;
    int b = bm / N3V, m = bm % N3V;
    float s = 0.f;
#pragma unroll
    for (int j = 0; j < 6; ++j) {
        int c = cols[m * 6 + j];
        s += vals[m * 6 + j] * bf2f(u[((size_t)b * N3V + c) * 384 + f]);
    }
    s += bf2f(u[(size_t)bm * 384 + 192 + f]) + bias[f];
    s = fmaxf(s, 0.f);
    if (mode) s = 0.5f * (bf2f(hprev[(size_t)bm * 192 + f]) + s);
    out[(size_t)bm * 192 + f] = f2bf(s);
}

// ---------------------------------------------------------------------------
// final head (fp32 weights, bf16 activations)
// ---------------------------------------------------------------------------
__global__ void head_a(const ushort* __restrict__ x4, const float* __restrict__ Wg,
                       const float* __restrict__ loopWg, float* __restrict__ t)
{
    int idx = blockIdx.x * 256 + threadIdx.x;
    if (idx >= MTOT * 6) return;
    int bm = idx / 6, c = idx % 6;
    const float* W = (c < 3) ? Wg : loopWg;
    int cc = (c < 3) ? c : c - 3;
    float s = 0.f;
    for (int k = 0; k < 192; ++k) s += bf2f(x4[(size_t)bm * 192 + k]) * W[k * 3 + cc];
    t[idx] = s;
}

__global__ void head_b(const float* __restrict__ t, const int* __restrict__ cols,
                       const float* __restrict__ vals, const float* __restrict__ bg,
                       float* __restrict__ out)
{
    int idx = blockIdx.x * 256 + threadIdx.x;
    if (idx >= MTOT * 3) return;
    int bm = idx / 3, c = idx % 3;
    int b = bm / N3V, m = bm % N3V;
    float s = 0.f;
#pragma unroll
    for (int j = 0; j < 6; ++j)
        s += vals[m * 6 + j] * t[((size_t)b * N3V + cols[m * 6 + j]) * 6 + c];
    s += t[(size_t)bm * 6 + 3 + c] + bg[c];
    out[idx] = s;
}

// ---------------------------------------------------------------------------
extern "C" void kernel_launch(void* const* d_in, const int* in_sizes, int n_in,
                              void* d_out, int out_size, void* d_ws, size_t ws_size,
                              hipStream_t stream)
{
    const float* x        = (const float*)d_in[0];
    const float* x2       = (const float*)d_in[1];
    const float* xh       = (const float*)d_in[2];
    const float* Wq       = (const float*)d_in[3];
    const float* bq       = (const float*)d_in[4];
    const float* Wk       = (const float*)d_in[5];
    const float* bk       = (const float*)d_in[6];
    const float* Wv       = (const float*)d_in[7];
    const float* bv       = (const float*)d_in[8];
    const float* adj      = (const float*)d_in[9];
    const int*   unpool   = (const int*)d_in[10];
    const float* W_in     = (const float*)d_in[11];
    const float* loopW_in = (const float*)d_in[12];
    const float* b_in     = (const float*)d_in[13];
    const float* res_W    = (const float*)d_in[14];
    const float* res_loopW= (const float*)d_in[15];
    const float* res_b    = (const float*)d_in[16];
    const float* W_out    = (const float*)d_in[17];
    const float* loopW_out= (const float*)d_in[18];
    const float* b_out    = (const float*)d_in[19];
    const float* Wg       = (const float*)d_in[20];
    const float* loopWg   = (const float*)d_in[21];
    const float* bg       = (const float*)d_in[22];
    float* out = (float*)d_out;

    char* ws = (char*)d_ws;
    size_t o = 0;
    auto alloc = [&](size_t bytes) { char* p = ws + o; o += (bytes + 255) & ~(size_t)255; return p; };
    float*  q    = (float*)alloc((size_t)NB * N2V * 8 * 4);
    float*  kbuf = (float*)alloc((size_t)NB * N2V * 8 * 4);
    float*  vbuf = (float*)alloc((size_t)NB * N2V * 8 * 4);
    float*  att  = (float*)alloc((size_t)NB * N2V * 8 * 4);
    int*    cols = (int*)alloc((size_t)N3V * 6 * 4);
    float*  vals = (float*)alloc((size_t)N3V * 6 * 4);
    ushort* F    = (ushort*)alloc((size_t)NB * N2V * KPAD * 2);
    ushort* wt_e = (ushort*)alloc((size_t)384 * KPAD * 2);
    ushort* wt_r = (ushort*)alloc((size_t)13 * 384 * 192 * 2);
    ushort* u    = (ushort*)alloc((size_t)MTOT * 384 * 2);
    ushort* h    = (ushort*)alloc((size_t)MTOT * 192 * 2);
    ushort* y    = (ushort*)alloc((size_t)MTOT * 192 * 2);
    float*  ts   = (float*)alloc((size_t)MTOT * 6 * 4);
    if (ws_size < o) return;

    qkv_kernel<<<(NB * N2V + 255) / 256, 256, 0, stream>>>(x2, Wq, bq, Wk, bk, Wv, bv, q, kbuf, vbuf);
    attn_kernel<<<NB * N2V, 256, 0, stream>>>(q, kbuf, vbuf, att);
    adj_extract<<<N3V, 256, 0, stream>>>(adj, cols, vals);
    build_F<<<NB * N2V, 256, 0, stream>>>(x, xh, att, F);
    prep_wt_entry<<<(384 * KPAD + 255) / 256, 256, 0, stream>>>(W_in, loopW_in, wt_e);
    for (int l = 0; l < 12; ++l)
        prep_wt192<<<(384 * 192 + 255) / 256, 256, 0, stream>>>(
            res_W + (size_t)l * 192 * 192, res_loopW + (size_t)l * 192 * 192,
            wt_r + (size_t)l * 384 * 192);
    prep_wt192<<<(384 * 192 + 255) / 256, 256, 0, stream>>>(
        W_out, loopW_out, wt_r + (size_t)12 * 384 * 192);

    int gblk = (MTOT + 63) / 64;   // 617
    mfma_gemm<true><<<gblk, 256, 0, stream>>>(nullptr, F, unpool, wt_e, u, KPAD);
    combine_bf<<<MTOT, 192, 0, stream>>>(u, cols, vals, b_in, nullptr, h, 0);

    for (int i = 0; i < 6; ++i) {
        const float* B0 = res_b + (size_t)(i * 2 + 0) * 192;
        const float* B1 = res_b + (size_t)(i * 2 + 1) * 192;
        mfma_gemm<false><<<gblk, 256, 0, stream>>>(h, nullptr, nullptr,
            wt_r + (size_t)(i * 2 + 0) * 384 * 192, u, 192);
        combine_bf<<<MTOT, 192, 0, stream>>>(u, cols, vals, B0, nullptr, y, 0);
        mfma_gemm<false><<<gblk, 256, 0, stream>>>(y, nullptr, nullptr,
            wt_r + (size_t)(i * 2 + 1) * 384 * 192, u, 192);
        combine_bf<<<MTOT, 192, 0, stream>>>(u, cols, vals, B1, h, h, 1);
    }

    mfma_gemm<false><<<gblk, 256, 0, stream>>>(h, nullptr, nullptr,
        wt_r + (size_t)12 * 384 * 192, u, 192);
    combine_bf<<<MTOT, 192, 0, stream>>>(u, cols, vals, b_out, nullptr, y, 0);

    head_a<<<(MTOT * 6 + 255) / 256, 256, 0, stream>>>(y, Wg, loopWg, ts);
    head_b<<<(MTOT * 3 + 255) / 256, 256, 0, stream>>>(ts, cols, vals, bg, out);
}